// Round 4
// baseline (613.269 us; speedup 1.0000x reference)
//
#include <hip/hip_runtime.h>

typedef short bf16x8 __attribute__((ext_vector_type(8)));
typedef short bf16x4 __attribute__((ext_vector_type(4)));
typedef float f32x4  __attribute__((ext_vector_type(4)));

static constexpr int Nd    = 50000;
static constexpr int Cd    = 256;
static constexpr int Hd    = 8;
static constexpr int Wd    = 256;
static constexpr int NWd   = (Nd + Wd - 1) / Wd;   // 196
static constexpr int NROWS = 2 * Nd;               // 100000

#define DEV static __device__ __forceinline__

DEV short f2bf(float f) {
  unsigned u = __float_as_uint(f);
  u += 0x7fffu + ((u >> 16) & 1u);   // round-to-nearest-even
  return (short)(u >> 16);
}

DEV bf16x8 ldfrag(const short* p) {
  // two-half k layout: k = 4*(lane>>4)+j and k = 16 + 4*(lane>>4)+j.
  // Any k-permutation error cancels because A and B use the same rule.
  bf16x4 a = *(const bf16x4*)(p);
  bf16x4 b = *(const bf16x4*)(p + 16);
  return __builtin_shufflevector(a, b, 0, 1, 2, 3, 4, 5, 6, 7);
}

DEV f32x4 mfma16(bf16x8 a, bf16x8 b, f32x4 c) {
  return __builtin_amdgcn_mfma_f32_16x16x32_bf16(a, b, c, 0, 0, 0);
}

// ---------------------------------------------------------------------------
// K1: fused QKV-projection + windowed attention. One block per (batch,window).
// Writes O (attention output, pre-proj) as fp32 into d_out.
// ---------------------------------------------------------------------------
__global__ __launch_bounds__(512, 2)
void wattn_qkv_attn(const float* __restrict__ x,
                    const float* __restrict__ qkv_w,
                    const float* __restrict__ qkv_b,
                    float* __restrict__ out)
{
  // LDS regions (shorts), aliased by lifetime:
  //  [0,9216)      Xs[256][36] (k-loop)  -> Qs[256][36] (writeout..S) -> Ps[256][36] (PV)
  //  [9216,12672)  Wt[96][36]  (k-loop)
  //  [12672,21888) Ks[256][36]
  //  [21888,30208) Vt[32][260]   (V transposed: [head_dim][key])
  __shared__ short lds[30208];
  short (*Xs)[36]  = (short(*)[36]) (lds);
  short (*Qs)[36]  = (short(*)[36]) (lds);
  short (*Ps)[36]  = (short(*)[36]) (lds);
  short (*Wt)[36]  = (short(*)[36]) (lds + 9216);
  short (*Ks)[36]  = (short(*)[36]) (lds + 12672);
  short (*Vt)[260] = (short(*)[260])(lds + 21888);

  const int blk = blockIdx.x;
  const int b   = blk / NWd;
  const int w   = blk % NWd;
  const int n0  = w * Wd;
  const int valid = (Nd - n0 < Wd) ? (Nd - n0) : Wd;   // rows of this window in-bounds

  const float* xw = x   + ((size_t)b * Nd + n0) * Cd;
  float*       ow = out + ((size_t)b * Nd + n0) * Cd;

  const int tid  = threadIdx.x;
  const int wid  = tid >> 6;
  const int lane = tid & 63;
  const int l15  = lane & 15;
  const int l4   = lane >> 4;
  const int rb   = wid * 32;            // this wave's 32 rows of the window
  const float scale = 0.1767766952966369f;  // 1/sqrt(32)

  for (int h = 0; h < Hd; ++h) {
    // ---------------- QKV GEMM for head h: [256 rows] x [96 cols], K=256 ----
    f32x4 acc[2][6];
#pragma unroll
    for (int i = 0; i < 2; ++i)
#pragma unroll
      for (int j = 0; j < 6; ++j) acc[i][j] = (f32x4){0.f, 0.f, 0.f, 0.f};

    for (int kc = 0; kc < 8; ++kc) {
      __syncthreads();   // protect LDS reuse (prev iter reads / prev head PV)
      // stage X chunk [256 rows][32 k] fp32 -> bf16 (zero-pad rows >= valid)
#pragma unroll
      for (int i = 0; i < 4; ++i) {
        int idx = tid + i * 512;          // 0..2047
        int row = idx >> 3;
        int q   = (idx & 7) * 4;
        float4 v = make_float4(0.f, 0.f, 0.f, 0.f);
        if (row < valid) v = *(const float4*)&xw[(size_t)row * Cd + kc * 32 + q];
        bf16x4 s4 = { f2bf(v.x), f2bf(v.y), f2bf(v.z), f2bf(v.w) };
        *(bf16x4*)&Xs[row][q] = s4;
      }
      // stage W chunk transposed: sections Q,K,V each [32 k][32 n] -> Wt[sec*32+n][k]
#pragma unroll
      for (int i = 0; i < 6; ++i) {
        int idx = tid + i * 512;          // 0..3071
        int sec = idx >> 10;              // 0=Q 1=K 2=V
        int k   = (idx >> 5) & 31;
        int n   = idx & 31;
        float v = qkv_w[(size_t)(kc * 32 + k) * (3 * Cd) + sec * Cd + h * 32 + n];
        Wt[sec * 32 + n][k] = f2bf(v);
      }
      __syncthreads();
      bf16x8 a0 = ldfrag(&Xs[rb + l15][l4 * 4]);
      bf16x8 a1 = ldfrag(&Xs[rb + 16 + l15][l4 * 4]);
#pragma unroll
      for (int fc = 0; fc < 6; ++fc) {
        bf16x8 bb = ldfrag(&Wt[fc * 16 + l15][l4 * 4]);
        acc[0][fc] = mfma16(a0, bb, acc[0][fc]);
        acc[1][fc] = mfma16(a1, bb, acc[1][fc]);
      }
    }

    // ---------------- write Q,K,V to LDS (wave-private rows, no race) ------
    // C/D layout: col = lane&15, row = 4*(lane>>4)+reg (HW-verified).
#pragma unroll
    for (int fc = 0; fc < 6; ++fc) {
      int sec  = fc >> 1;
      int colh = (fc & 1) * 16 + l15;           // 0..31 within section
      float bias = qkv_b[sec * Cd + h * 32 + colh];
#pragma unroll
      for (int fr = 0; fr < 2; ++fr) {
        int row0 = rb + fr * 16 + l4 * 4;
        f32x4 v = acc[fr][fc];
        if (sec == 0) {
#pragma unroll
          for (int r = 0; r < 4; ++r) Qs[row0 + r][colh] = f2bf((v[r] + bias) * scale);
        } else if (sec == 1) {
#pragma unroll
          for (int r = 0; r < 4; ++r) Ks[row0 + r][colh] = f2bf(v[r] + bias);
        } else {
          bf16x4 s4 = { f2bf(v[0] + bias), f2bf(v[1] + bias),
                        f2bf(v[2] + bias), f2bf(v[3] + bias) };
          *(bf16x4*)&Vt[colh][row0] = s4;       // transposed store, contiguous keys
        }
      }
    }
    __syncthreads();   // K,V visible to all waves

    // ---------------- S = Q K^T (this wave's 32 rows x 256 keys) -----------
    bf16x8 qa0 = ldfrag(&Qs[rb + l15][l4 * 4]);
    bf16x8 qa1 = ldfrag(&Qs[rb + 16 + l15][l4 * 4]);
    f32x4 s[2][16];
#pragma unroll
    for (int fc = 0; fc < 16; ++fc) {
      bf16x8 kb = ldfrag(&Ks[fc * 16 + l15][l4 * 4]);
      f32x4 z = (f32x4){0.f, 0.f, 0.f, 0.f};
      s[0][fc] = mfma16(qa0, kb, z);
      s[1][fc] = mfma16(qa1, kb, z);
    }

    // ---------------- softmax over keys (deferred normalization) -----------
    float sminv[2][4];
#pragma unroll
    for (int fr = 0; fr < 2; ++fr)
#pragma unroll
      for (int r = 0; r < 4; ++r) {
        float m = -1e30f;
#pragma unroll
        for (int fc = 0; fc < 16; ++fc) m = fmaxf(m, s[fr][fc][r]);
#pragma unroll
        for (int d = 1; d < 16; d <<= 1) m = fmaxf(m, __shfl_xor(m, d));
        float t = 0.f;
#pragma unroll
        for (int fc = 0; fc < 16; ++fc) {
          float e = __expf(s[fr][fc][r] - m);
          s[fr][fc][r] = e;
          t += e;
        }
#pragma unroll
        for (int d = 1; d < 16; d <<= 1) t += __shfl_xor(t, d);
        sminv[fr][r] = 1.f / t;
      }

    // ---------------- O = P V, key-chunks of 32 (P via wave-private LDS) ---
    f32x4 o[2][2];
    o[0][0] = o[0][1] = o[1][0] = o[1][1] = (f32x4){0.f, 0.f, 0.f, 0.f};
#pragma unroll
    for (int c = 0; c < 8; ++c) {
#pragma unroll
      for (int fr = 0; fr < 2; ++fr)
#pragma unroll
        for (int fc2 = 0; fc2 < 2; ++fc2) {
          f32x4 v = s[fr][c * 2 + fc2];
          int row0 = rb + fr * 16 + l4 * 4;
#pragma unroll
          for (int r = 0; r < 4; ++r)
            Ps[row0 + r][fc2 * 16 + l15] = f2bf(v[r]);
        }
      bf16x8 pa0 = ldfrag(&Ps[rb + l15][l4 * 4]);
      bf16x8 pa1 = ldfrag(&Ps[rb + 16 + l15][l4 * 4]);
#pragma unroll
      for (int fc2 = 0; fc2 < 2; ++fc2) {
        bf16x8 vb = ldfrag(&Vt[fc2 * 16 + l15][c * 32 + l4 * 4]);
        o[0][fc2] = mfma16(pa0, vb, o[0][fc2]);
        o[1][fc2] = mfma16(pa1, vb, o[1][fc2]);
      }
    }

    // ---------------- write O (normalized) to d_out ------------------------
#pragma unroll
    for (int fr = 0; fr < 2; ++fr)
#pragma unroll
      for (int fc2 = 0; fc2 < 2; ++fc2)
#pragma unroll
        for (int r = 0; r < 4; ++r) {
          int row = rb + fr * 16 + l4 * 4 + r;
          if (row < valid)
            ow[(size_t)row * Cd + h * 32 + fc2 * 16 + l15] = o[fr][fc2][r] * sminv[fr][r];
        }
  }
}

// ---------------------------------------------------------------------------
// K2: in-place output projection on d_out. Each block fully stages its own
// 256 rows into LDS before overwriting them (in-place safe; rows disjoint
// across blocks).
// ---------------------------------------------------------------------------
__global__ __launch_bounds__(512, 2)
void wattn_proj(float* data,
                const float* __restrict__ proj_w,
                const float* __restrict__ proj_b)
{
  __shared__ short Os[256][36];
  __shared__ short Wt[256][36];

  const int r0   = blockIdx.x * 256;
  const int tid  = threadIdx.x;
  const int wid  = tid >> 6;
  const int lane = tid & 63;
  const int l15  = lane & 15;
  const int l4   = lane >> 4;
  const int rb   = wid * 32;

  f32x4 acc[2][16];
#pragma unroll
  for (int i = 0; i < 2; ++i)
#pragma unroll
    for (int j = 0; j < 16; ++j) acc[i][j] = (f32x4){0.f, 0.f, 0.f, 0.f};

  for (int kc = 0; kc < 8; ++kc) {
    __syncthreads();
#pragma unroll
    for (int i = 0; i < 4; ++i) {
      int idx = tid + i * 512;
      int row = idx >> 3;
      int q   = (idx & 7) * 4;
      float4 v = make_float4(0.f, 0.f, 0.f, 0.f);
      if (r0 + row < NROWS) v = *(const float4*)&data[(size_t)(r0 + row) * Cd + kc * 32 + q];
      bf16x4 s4 = { f2bf(v.x), f2bf(v.y), f2bf(v.z), f2bf(v.w) };
      *(bf16x4*)&Os[row][q] = s4;
    }
#pragma unroll
    for (int i = 0; i < 16; ++i) {
      int idx = tid + i * 512;          // 0..8191
      int k = idx >> 8;
      int n = idx & 255;
      Wt[n][k] = f2bf(proj_w[(size_t)(kc * 32 + k) * Cd + n]);
    }
    __syncthreads();
    bf16x8 a0 = ldfrag(&Os[rb + l15][l4 * 4]);
    bf16x8 a1 = ldfrag(&Os[rb + 16 + l15][l4 * 4]);
#pragma unroll
    for (int fc = 0; fc < 16; ++fc) {
      bf16x8 bb = ldfrag(&Wt[fc * 16 + l15][l4 * 4]);
      acc[0][fc] = mfma16(a0, bb, acc[0][fc]);
      acc[1][fc] = mfma16(a1, bb, acc[1][fc]);
    }
  }

#pragma unroll
  for (int fc = 0; fc < 16; ++fc) {
    float bias = proj_b[fc * 16 + l15];
#pragma unroll
    for (int fr = 0; fr < 2; ++fr) {
      int row0 = r0 + rb + fr * 16 + l4 * 4;
#pragma unroll
      for (int r = 0; r < 4; ++r)
        if (row0 + r < NROWS)
          data[(size_t)(row0 + r) * Cd + fc * 16 + l15] = acc[fr][fc][r] + bias;
    }
  }
}

extern "C" void kernel_launch(void* const* d_in, const int* in_sizes, int n_in,
                              void* d_out, int out_size, void* d_ws, size_t ws_size,
                              hipStream_t stream) {
  const float* x      = (const float*)d_in[0];
  const float* qkv_w  = (const float*)d_in[1];
  const float* qkv_b  = (const float*)d_in[2];
  const float* proj_w = (const float*)d_in[3];
  const float* proj_b = (const float*)d_in[4];
  float* out = (float*)d_out;

  wattn_qkv_attn<<<dim3(2 * NWd), dim3(512), 0, stream>>>(x, qkv_w, qkv_b, out);
  wattn_proj<<<dim3((NROWS + 255) / 256), dim3(512), 0, stream>>>(out, proj_w, proj_b);
}